// Round 1
// baseline (19.841 us; speedup 1.0000x reference)
//
#include <hip/hip_runtime.h>

#define BATCH 8192
#define FEAT  512

__global__ __launch_bounds__(256) void center_loss_kernel(
    const float* __restrict__ features,
    const int*   __restrict__ labels,
    const float* __restrict__ centers,
    float*       __restrict__ out)
{
    const int lane          = threadIdx.x & 63;
    const int wave_in_block = threadIdx.x >> 6;
    const int waves_per_blk = blockDim.x >> 6;
    const int wave_id       = blockIdx.x * waves_per_blk + wave_in_block;
    const int num_waves     = gridDim.x * waves_per_blk;

    float acc = 0.0f;
    for (int row = wave_id; row < BATCH; row += num_waves) {
        const int lbl = labels[row];
        const float4* f = reinterpret_cast<const float4*>(features + (size_t)row * FEAT);
        const float4* c = reinterpret_cast<const float4*>(centers  + (size_t)lbl * FEAT);
        // 512 floats = 128 float4; 64 lanes -> 2 float4 per lane, coalesced.
        float4 f0 = f[lane];
        float4 c0 = c[lane];
        float4 f1 = f[lane + 64];
        float4 c1 = c[lane + 64];
        float d;
        d = f0.x - c0.x; acc += d * d;
        d = f0.y - c0.y; acc += d * d;
        d = f0.z - c0.z; acc += d * d;
        d = f0.w - c0.w; acc += d * d;
        d = f1.x - c1.x; acc += d * d;
        d = f1.y - c1.y; acc += d * d;
        d = f1.z - c1.z; acc += d * d;
        d = f1.w - c1.w; acc += d * d;
    }

    // wave-level butterfly reduce (64 lanes)
    #pragma unroll
    for (int off = 32; off > 0; off >>= 1)
        acc += __shfl_down(acc, off, 64);

    __shared__ float smem[4];
    if (lane == 0) smem[wave_in_block] = acc;
    __syncthreads();
    if (threadIdx.x == 0) {
        float s = 0.0f;
        for (int w = 0; w < waves_per_blk; ++w) s += smem[w];
        atomicAdd(out, s * (1.0f / BATCH));
    }
}

extern "C" void kernel_launch(void* const* d_in, const int* in_sizes, int n_in,
                              void* d_out, int out_size, void* d_ws, size_t ws_size,
                              hipStream_t stream) {
    const float* features = (const float*)d_in[0];
    const int*   labels   = (const int*)d_in[1];
    const float* centers  = (const float*)d_in[2];
    float* out = (float*)d_out;

    // d_out is poisoned (0xAA) before timing and never re-poisoned between
    // replays -> must zero it ourselves every call (async, capture-safe).
    hipMemsetAsync(out, 0, sizeof(float), stream);

    const int block = 256;
    const int grid  = 512;  // 2048 waves, 4 rows per wave
    center_loss_kernel<<<grid, block, 0, stream>>>(features, labels, centers, out);
}

// Round 2
// 10.925 us; speedup vs baseline: 1.8161x; 1.8161x over previous
//
#include <hip/hip_runtime.h>

#define BATCH 8192
#define FEAT  512
#define NBLK1 (BATCH / 4)   // 2048 blocks, 4 waves/block, one wave per row

__global__ __launch_bounds__(256) void center_loss_partial(
    const float* __restrict__ features,
    const int*   __restrict__ labels,
    const float* __restrict__ centers,
    float*       __restrict__ partials)
{
    const int lane = threadIdx.x & 63;
    const int wave = threadIdx.x >> 6;
    const int row  = blockIdx.x * 4 + wave;

    // label is wave-uniform; issue it first, feature loads overlap the latency
    const int lbl = labels[row];
    const float4* f = reinterpret_cast<const float4*>(features + (size_t)row * FEAT);
    const float4* c = reinterpret_cast<const float4*>(centers  + (size_t)lbl * FEAT);

    // 512 floats = 128 float4; 64 lanes -> 2 float4 each, 1 KB coalesced per load
    float4 f0 = f[lane];
    float4 f1 = f[lane + 64];
    float4 c0 = c[lane];
    float4 c1 = c[lane + 64];

    float acc, d;
    d = f0.x - c0.x; acc  = d * d;
    d = f0.y - c0.y; acc += d * d;
    d = f0.z - c0.z; acc += d * d;
    d = f0.w - c0.w; acc += d * d;
    d = f1.x - c1.x; acc += d * d;
    d = f1.y - c1.y; acc += d * d;
    d = f1.z - c1.z; acc += d * d;
    d = f1.w - c1.w; acc += d * d;

    #pragma unroll
    for (int off = 32; off > 0; off >>= 1)
        acc += __shfl_down(acc, off, 64);

    __shared__ float smem[4];
    if (lane == 0) smem[wave] = acc;
    __syncthreads();
    if (threadIdx.x == 0)
        partials[blockIdx.x] = smem[0] + smem[1] + smem[2] + smem[3];
}

__global__ __launch_bounds__(256) void center_loss_reduce(
    const float* __restrict__ partials,
    float*       __restrict__ out)
{
    // 2048 partials / 256 threads = 8 each (2x float4)
    const float4* p = reinterpret_cast<const float4*>(partials);
    float4 a = p[threadIdx.x];
    float4 b = p[threadIdx.x + 256];
    float s = (a.x + a.y + a.z + a.w) + (b.x + b.y + b.z + b.w);

    #pragma unroll
    for (int off = 32; off > 0; off >>= 1)
        s += __shfl_down(s, off, 64);

    __shared__ float smem[4];
    const int lane = threadIdx.x & 63;
    const int wave = threadIdx.x >> 6;
    if (lane == 0) smem[wave] = s;
    __syncthreads();
    if (threadIdx.x == 0)
        out[0] = (smem[0] + smem[1] + smem[2] + smem[3]) * (1.0f / BATCH);
}

extern "C" void kernel_launch(void* const* d_in, const int* in_sizes, int n_in,
                              void* d_out, int out_size, void* d_ws, size_t ws_size,
                              hipStream_t stream) {
    const float* features = (const float*)d_in[0];
    const int*   labels   = (const int*)d_in[1];
    const float* centers  = (const float*)d_in[2];
    float* out      = (float*)d_out;
    float* partials = (float*)d_ws;   // 2048 floats, written unconditionally each call

    center_loss_partial<<<NBLK1, 256, 0, stream>>>(features, labels, centers, partials);
    center_loss_reduce<<<1, 256, 0, stream>>>(partials, out);
}